// Round 12
// baseline (73.814 us; speedup 1.0000x reference)
//
#include <hip/hip_runtime.h>
#include <type_traits>

#define IMG_W 256
#define IMG_H 256
#define EPSN 1e-7f
#define NS 50.0f            // 1/(2*0.1^2)
#define NB 16
#define NN 64
#define NC 3
#define PH 32
#define PW 32
#define WIN 36
#define NWG 2048            // blocks for all variants (192 threads)

// ======================= variant A: R9 base (control) =======================
__global__ __launch_bounds__(192)
void fusedA_base(const float* __restrict__ brushes,
                 const float* __restrict__ patches,
                 float* __restrict__ out) {
    __shared__ float2 sG[NN];
    __shared__ int    sN[NN];
    __shared__ int    sCnt;

    int blk = blockIdx.x;
    blk = (blk & 7) * (NWG >> 3) + (blk >> 3);

    const int b    = blk >> 7;
    const int t7   = blk & 127;
    const int ty0  = (t7 >> 2) * 8;
    const int tx0  = (t7 & 3) * 64;
    const int tid  = threadIdx.x;
    const int cc   = tid >> 6;
    const int lane = tid & 63;
    const int ysub = lane >> 4;
    const int xgrp = lane & 15;
    const int ax0  = tx0 + xgrp * 4;
    const int ay0  = ty0 + ysub * 2;

    if (tid < 64) {
        float2 v = ((const float2*)brushes)[b * NN + tid];
        float mnx = v.x, mxx = v.x, mny = v.y, mxy = v.y;
        #pragma unroll
        for (int off = 32; off > 0; off >>= 1) {
            mnx = fminf(mnx, __shfl_xor(mnx, off));
            mxx = fmaxf(mxx, __shfl_xor(mxx, off));
            mny = fminf(mny, __shfl_xor(mny, off));
            mxy = fmaxf(mxy, __shfl_xor(mxy, off));
        }
        float gx = (v.x - mnx) / (mxx - mnx + EPSN) * (float)IMG_W;
        float gy = (v.y - mny) / (mxy - mny + EPSN) * (float)IMG_H;
        int ix0 = (int)floorf(gx) - 17;
        int iy0 = (int)floorf(gy) - 17;
        bool ov = (ix0 <= tx0 + 63) && (ix0 + 35 >= tx0) &&
                  (iy0 <= ty0 + 7)  && (iy0 + 35 >= ty0);
        unsigned long long mask = __ballot(ov);
        if (ov) {
            int pos = __popcll(mask & ((1ull << tid) - 1));
            sN[pos] = tid;
            sG[pos] = make_float2(gx, gy);
        }
        if (tid == 0) sCnt = (int)__popcll(mask);
    }
    __syncthreads();
    const int cnt = sCnt;

    float acc[2][4];
    #pragma unroll
    for (int j = 0; j < 2; ++j)
        #pragma unroll
        for (int o = 0; o < 4; ++o) acc[j][o] = 0.f;

    const float* Pcb = patches + (size_t)b * NN * (NC * PH * PW) + cc * (PH * PW);

    for (int i = 0; i < cnt; ++i) {
        const float2 g = sG[i];
        const int    n = sN[i];
        const float* Pc = Pcb + (size_t)n * (NC * PH * PW);

        const float zy0 = (float)ty0 - g.y + 15.4f;
        const int pbase = (int)floorf(zy0) - 1;
        const float zx0 = (float)ax0 - g.x + 15.5f;
        const int   q00 = (int)floorf(zx0) - 1;

        if (q00 >= -6 && q00 <= 31) {
            const float phx = zx0 - floorf(zx0);
            float Ex[4], W[4];
            #pragma unroll
            for (int k = 0; k < 4; ++k) {
                float d = phx + (float)(1 - k);
                Ex[k] = __expf(-NS * d * d);
            }
            float Sx  = ((Ex[0] + Ex[1]) + (Ex[2] + Ex[3]));
            float Dxc = 1.f / (Sx + EPSN);
            #pragma unroll
            for (int k = 0; k < 4; ++k) W[k] = Ex[k] * Dxc;

            const int qg = ((q00 + 8) & ~3) - 8;
            const int M  = (q00 + 8) & 3;
            const int s1 = qg + 4, s2 = qg + 8;
            const float m0 = (qg >= 0 && qg <= 28) ? 1.f : 0.f;
            const float m1 = (s1 >= 0 && s1 <= 28) ? 1.f : 0.f;
            const float m2 = (s2 >= 0 && s2 <= 28) ? 1.f : 0.f;
            const int c0 = min(max(qg, 0), 28);
            const int c1 = min(max(s1, 0), 28);
            const int c2 = min(max(s2, 0), 28);

            float t[5][4];
            auto rows = [&](auto Mc) {
                constexpr int Mv = Mc.value;
                #pragma unroll
                for (int rr = 0; rr < 5; ++rr) {
                    int src = min(max(pbase + 2 * ysub + rr, 0), 31);
                    const float* rp = Pc + (src << 5);
                    float4 A  = *(const float4*)(rp + c0);
                    float4 Bv = *(const float4*)(rp + c1);
                    float4 Cv = *(const float4*)(rp + c2);
                    float pv[12] = {A.x * m0, A.y * m0, A.z * m0, A.w * m0,
                                    Bv.x * m1, Bv.y * m1, Bv.z * m1, Bv.w * m1,
                                    Cv.x * m2, Cv.y * m2, Cv.z * m2, Cv.w * m2};
                    #pragma unroll
                    for (int o = 0; o < 4; ++o)
                        t[rr][o] = W[0] * pv[Mv + o]     + W[1] * pv[Mv + o + 1]
                                 + W[2] * pv[Mv + o + 2] + W[3] * pv[Mv + o + 3];
                }
            };
            switch (M) {
                case 0: rows(std::integral_constant<int, 0>{}); break;
                case 1: rows(std::integral_constant<int, 1>{}); break;
                case 2: rows(std::integral_constant<int, 2>{}); break;
                default: rows(std::integral_constant<int, 3>{}); break;
            }

            if (g.x > 255.0f) {
                float cx31 = g.x + 15.5f;
                float dc   = 272.f - cx31;
                float c272 = __expf(-NS * dc * dc);
                float dD   = 1.f / (Sx - c272 + EPSN) - Dxc;
                float e31[4];
                #pragma unroll
                for (int o = 0; o < 4; ++o) {
                    float d = zx0 + (float)o - 31.f;
                    e31[o] = __expf(-NS * d * d) * dD;
                }
                #pragma unroll
                for (int rr = 0; rr < 5; ++rr) {
                    int src = min(max(pbase + 2 * ysub + rr, 0), 31);
                    float p31 = Pc[(src << 5) + 31];
                    #pragma unroll
                    for (int o = 0; o < 4; ++o) t[rr][o] += e31[o] * p31;
                }
            }

            const float psy = zy0 - floorf(zy0);
            float Ey[4];
            #pragma unroll
            for (int k = 0; k < 4; ++k) {
                float d = psy + (float)(1 - k);
                Ey[k] = __expf(-NS * d * d);
            }
            float Sy   = ((Ey[0] + Ey[1]) + (Ey[2] + Ey[3]));
            float DyC  = (1.f / (Sy + EPSN)) * (1.0f / (float)NN);
            float Dy31 = DyC;
            if (g.y > 254.9f) {
                float cy31 = g.y + 15.6f;
                float dc   = 272.f - cy31;
                float c272 = __expf(-NS * dc * dc);
                Dy31 = (1.f / (Sy - c272 + EPSN)) * (1.0f / (float)NN);
            }
            float wyA[4], wyB[4];
            #pragma unroll
            for (int k = 0; k < 4; ++k) {
                int rA = pbase + 2 * ysub + k;
                int rB = rA + 1;
                wyA[k] = ((unsigned)rA < 32u) ? Ey[k] * ((rA == 31) ? Dy31 : DyC) : 0.f;
                wyB[k] = ((unsigned)rB < 32u) ? Ey[k] * ((rB == 31) ? Dy31 : DyC) : 0.f;
            }
            #pragma unroll
            for (int o = 0; o < 4; ++o) {
                acc[0][o] += wyA[0] * t[0][o] + wyA[1] * t[1][o]
                           + wyA[2] * t[2][o] + wyA[3] * t[3][o];
                acc[1][o] += wyB[0] * t[1][o] + wyB[1] * t[2][o]
                           + wyB[2] * t[3][o] + wyB[3] * t[4][o];
            }
        }
    }

    #pragma unroll
    for (int j = 0; j < 2; ++j) {
        float* o = out + (((size_t)b * NC + cc) * IMG_H + ay0 + j) * IMG_W + ax0;
        *(float4*)o = make_float4(acc[j][0], acc[j][1], acc[j][2], acc[j][3]);
    }
}

// ================= variant B: compact 32x16 wave footprint ==================
__global__ __launch_bounds__(192)
void fusedB_t32x16(const float* __restrict__ brushes,
                   const float* __restrict__ patches,
                   float* __restrict__ out) {
    __shared__ float2 sG[NN];
    __shared__ int    sN[NN];
    __shared__ int    sCnt;

    int blk = blockIdx.x;
    blk = (blk & 7) * (NWG >> 3) + (blk >> 3);

    const int b    = blk >> 7;
    const int t7   = blk & 127;
    const int ty0  = (t7 >> 3) * 16;            // 16 y-tiles
    const int tx0  = (t7 & 7) * 32;             // 8 x-tiles
    const int tid  = threadIdx.x;
    const int cc   = tid >> 6;
    const int lane = tid & 63;
    const int ysub = lane >> 3;                 // 0..7
    const int xgrp = lane & 7;                  // 0..7
    const int ax0  = tx0 + xgrp * 4;
    const int ay0  = ty0 + ysub * 2;

    if (tid < 64) {
        float2 v = ((const float2*)brushes)[b * NN + tid];
        float mnx = v.x, mxx = v.x, mny = v.y, mxy = v.y;
        #pragma unroll
        for (int off = 32; off > 0; off >>= 1) {
            mnx = fminf(mnx, __shfl_xor(mnx, off));
            mxx = fmaxf(mxx, __shfl_xor(mxx, off));
            mny = fminf(mny, __shfl_xor(mny, off));
            mxy = fmaxf(mxy, __shfl_xor(mxy, off));
        }
        float gx = (v.x - mnx) / (mxx - mnx + EPSN) * (float)IMG_W;
        float gy = (v.y - mny) / (mxy - mny + EPSN) * (float)IMG_H;
        int ix0 = (int)floorf(gx) - 17;
        int iy0 = (int)floorf(gy) - 17;
        bool ov = (ix0 <= tx0 + 31) && (ix0 + 35 >= tx0) &&
                  (iy0 <= ty0 + 15) && (iy0 + 35 >= ty0);
        unsigned long long mask = __ballot(ov);
        if (ov) {
            int pos = __popcll(mask & ((1ull << tid) - 1));
            sN[pos] = tid;
            sG[pos] = make_float2(gx, gy);
        }
        if (tid == 0) sCnt = (int)__popcll(mask);
    }
    __syncthreads();
    const int cnt = sCnt;

    float acc[2][4];
    #pragma unroll
    for (int j = 0; j < 2; ++j)
        #pragma unroll
        for (int o = 0; o < 4; ++o) acc[j][o] = 0.f;

    const float* Pcb = patches + (size_t)b * NN * (NC * PH * PW) + cc * (PH * PW);

    for (int i = 0; i < cnt; ++i) {
        const float2 g = sG[i];
        const int    n = sN[i];
        const float* Pc = Pcb + (size_t)n * (NC * PH * PW);

        const float zy0 = (float)ty0 - g.y + 15.4f;
        const int pbase = (int)floorf(zy0) - 1;
        const float zx0 = (float)ax0 - g.x + 15.5f;
        const int   q00 = (int)floorf(zx0) - 1;

        if (q00 >= -6 && q00 <= 31) {
            const float phx = zx0 - floorf(zx0);
            float Ex[4], W[4];
            #pragma unroll
            for (int k = 0; k < 4; ++k) {
                float d = phx + (float)(1 - k);
                Ex[k] = __expf(-NS * d * d);
            }
            float Sx  = ((Ex[0] + Ex[1]) + (Ex[2] + Ex[3]));
            float Dxc = 1.f / (Sx + EPSN);
            #pragma unroll
            for (int k = 0; k < 4; ++k) W[k] = Ex[k] * Dxc;

            const int qg = ((q00 + 8) & ~3) - 8;
            const int M  = (q00 + 8) & 3;
            const int s1 = qg + 4, s2 = qg + 8;
            const float m0 = (qg >= 0 && qg <= 28) ? 1.f : 0.f;
            const float m1 = (s1 >= 0 && s1 <= 28) ? 1.f : 0.f;
            const float m2 = (s2 >= 0 && s2 <= 28) ? 1.f : 0.f;
            const int c0 = min(max(qg, 0), 28);
            const int c1 = min(max(s1, 0), 28);
            const int c2 = min(max(s2, 0), 28);

            float t[5][4];
            auto rows = [&](auto Mc) {
                constexpr int Mv = Mc.value;
                #pragma unroll
                for (int rr = 0; rr < 5; ++rr) {
                    int src = min(max(pbase + 2 * ysub + rr, 0), 31);
                    const float* rp = Pc + (src << 5);
                    float4 A  = *(const float4*)(rp + c0);
                    float4 Bv = *(const float4*)(rp + c1);
                    float4 Cv = *(const float4*)(rp + c2);
                    float pv[12] = {A.x * m0, A.y * m0, A.z * m0, A.w * m0,
                                    Bv.x * m1, Bv.y * m1, Bv.z * m1, Bv.w * m1,
                                    Cv.x * m2, Cv.y * m2, Cv.z * m2, Cv.w * m2};
                    #pragma unroll
                    for (int o = 0; o < 4; ++o)
                        t[rr][o] = W[0] * pv[Mv + o]     + W[1] * pv[Mv + o + 1]
                                 + W[2] * pv[Mv + o + 2] + W[3] * pv[Mv + o + 3];
                }
            };
            switch (M) {
                case 0: rows(std::integral_constant<int, 0>{}); break;
                case 1: rows(std::integral_constant<int, 1>{}); break;
                case 2: rows(std::integral_constant<int, 2>{}); break;
                default: rows(std::integral_constant<int, 3>{}); break;
            }

            if (g.x > 255.0f) {
                float cx31 = g.x + 15.5f;
                float dc   = 272.f - cx31;
                float c272 = __expf(-NS * dc * dc);
                float dD   = 1.f / (Sx - c272 + EPSN) - Dxc;
                float e31[4];
                #pragma unroll
                for (int o = 0; o < 4; ++o) {
                    float d = zx0 + (float)o - 31.f;
                    e31[o] = __expf(-NS * d * d) * dD;
                }
                #pragma unroll
                for (int rr = 0; rr < 5; ++rr) {
                    int src = min(max(pbase + 2 * ysub + rr, 0), 31);
                    float p31 = Pc[(src << 5) + 31];
                    #pragma unroll
                    for (int o = 0; o < 4; ++o) t[rr][o] += e31[o] * p31;
                }
            }

            const float psy = zy0 - floorf(zy0);
            float Ey[4];
            #pragma unroll
            for (int k = 0; k < 4; ++k) {
                float d = psy + (float)(1 - k);
                Ey[k] = __expf(-NS * d * d);
            }
            float Sy   = ((Ey[0] + Ey[1]) + (Ey[2] + Ey[3]));
            float DyC  = (1.f / (Sy + EPSN)) * (1.0f / (float)NN);
            float Dy31 = DyC;
            if (g.y > 254.9f) {
                float cy31 = g.y + 15.6f;
                float dc   = 272.f - cy31;
                float c272 = __expf(-NS * dc * dc);
                Dy31 = (1.f / (Sy - c272 + EPSN)) * (1.0f / (float)NN);
            }
            float wyA[4], wyB[4];
            #pragma unroll
            for (int k = 0; k < 4; ++k) {
                int rA = pbase + 2 * ysub + k;
                int rB = rA + 1;
                wyA[k] = ((unsigned)rA < 32u) ? Ey[k] * ((rA == 31) ? Dy31 : DyC) : 0.f;
                wyB[k] = ((unsigned)rB < 32u) ? Ey[k] * ((rB == 31) ? Dy31 : DyC) : 0.f;
            }
            #pragma unroll
            for (int o = 0; o < 4; ++o) {
                acc[0][o] += wyA[0] * t[0][o] + wyA[1] * t[1][o]
                           + wyA[2] * t[2][o] + wyA[3] * t[3][o];
                acc[1][o] += wyB[0] * t[1][o] + wyB[1] * t[2][o]
                           + wyB[2] * t[3][o] + wyB[3] * t[4][o];
            }
        }
    }

    #pragma unroll
    for (int j = 0; j < 2; ++j) {
        float* o = out + (((size_t)b * NC + cc) * IMG_H + ay0 + j) * IMG_W + ax0;
        *(float4*)o = make_float4(acc[j][0], acc[j][1], acc[j][2], acc[j][3]);
    }
}

// ============ variant C: A-geometry, B-chunk via neighbor __shfl ============
__global__ __launch_bounds__(192)
void fusedC_shfl(const float* __restrict__ brushes,
                 const float* __restrict__ patches,
                 float* __restrict__ out) {
    __shared__ float2 sG[NN];
    __shared__ int    sN[NN];
    __shared__ int    sCnt;

    int blk = blockIdx.x;
    blk = (blk & 7) * (NWG >> 3) + (blk >> 3);

    const int b    = blk >> 7;
    const int t7   = blk & 127;
    const int ty0  = (t7 >> 2) * 8;
    const int tx0  = (t7 & 3) * 64;
    const int tid  = threadIdx.x;
    const int cc   = tid >> 6;
    const int lane = tid & 63;
    const int ysub = lane >> 4;
    const int xgrp = lane & 15;
    const int ax0  = tx0 + xgrp * 4;
    const int ay0  = ty0 + ysub * 2;

    if (tid < 64) {
        float2 v = ((const float2*)brushes)[b * NN + tid];
        float mnx = v.x, mxx = v.x, mny = v.y, mxy = v.y;
        #pragma unroll
        for (int off = 32; off > 0; off >>= 1) {
            mnx = fminf(mnx, __shfl_xor(mnx, off));
            mxx = fmaxf(mxx, __shfl_xor(mxx, off));
            mny = fminf(mny, __shfl_xor(mny, off));
            mxy = fmaxf(mxy, __shfl_xor(mxy, off));
        }
        float gx = (v.x - mnx) / (mxx - mnx + EPSN) * (float)IMG_W;
        float gy = (v.y - mny) / (mxy - mny + EPSN) * (float)IMG_H;
        int ix0 = (int)floorf(gx) - 17;
        int iy0 = (int)floorf(gy) - 17;
        bool ov = (ix0 <= tx0 + 63) && (ix0 + 35 >= tx0) &&
                  (iy0 <= ty0 + 7)  && (iy0 + 35 >= ty0);
        unsigned long long mask = __ballot(ov);
        if (ov) {
            int pos = __popcll(mask & ((1ull << tid) - 1));
            sN[pos] = tid;
            sG[pos] = make_float2(gx, gy);
        }
        if (tid == 0) sCnt = (int)__popcll(mask);
    }
    __syncthreads();
    const int cnt = sCnt;

    float acc[2][4];
    #pragma unroll
    for (int j = 0; j < 2; ++j)
        #pragma unroll
        for (int o = 0; o < 4; ++o) acc[j][o] = 0.f;

    const float* Pcb = patches + (size_t)b * NN * (NC * PH * PW) + cc * (PH * PW);

    for (int i = 0; i < cnt; ++i) {
        const float2 g = sG[i];
        const int    n = sN[i];
        const float* Pc = Pcb + (size_t)n * (NC * PH * PW);

        const float zy0 = (float)ty0 - g.y + 15.4f;
        const int pbase = (int)floorf(zy0) - 1;
        const float zx0 = (float)ax0 - g.x + 15.5f;
        const int   q00 = (int)floorf(zx0) - 1;

        // widened window: shfl sources of any consumer in [-6,31] are executed
        if (q00 >= -10 && q00 <= 35) {
            const float phx = zx0 - floorf(zx0);
            float Ex[4], W[4];
            #pragma unroll
            for (int k = 0; k < 4; ++k) {
                float d = phx + (float)(1 - k);
                Ex[k] = __expf(-NS * d * d);
            }
            float Sx  = ((Ex[0] + Ex[1]) + (Ex[2] + Ex[3]));
            float Dxc = 1.f / (Sx + EPSN);
            #pragma unroll
            for (int k = 0; k < 4; ++k) W[k] = Ex[k] * Dxc;

            const int qg = ((q00 + 8) & ~3) - 8;
            const int M  = (q00 + 8) & 3;
            const int s1 = qg + 4, s2 = qg + 8;
            const float m0 = (qg >= 0 && qg <= 28) ? 1.f : 0.f;
            const bool  v1 = (s1 >= 0 && s1 <= 28);
            const float m2 = (s2 >= 0 && s2 <= 28) ? 1.f : 0.f;
            const int c0 = min(max(qg, 0), 28);
            const int c2 = min(max(s2, 0), 28);
            const bool hi = (xgrp == 15);
            const int upL = lane + 1, dnL = lane - 1;

            float t[5][4];
            auto rows = [&](auto Mc) {
                constexpr int Mv = Mc.value;
                #pragma unroll
                for (int rr = 0; rr < 5; ++rr) {
                    int src = min(max(pbase + 2 * ysub + rr, 0), 31);
                    const float* rp = Pc + (src << 5);
                    float4 A  = *(const float4*)(rp + c0);
                    float4 Cv = *(const float4*)(rp + c2);
                    // B chunk = neighbor's A (or C for the last xgrp)
                    float ba0 = __shfl(A.x, upL), bc0 = __shfl(Cv.x, dnL);
                    float ba1 = __shfl(A.y, upL), bc1 = __shfl(Cv.y, dnL);
                    float ba2 = __shfl(A.z, upL), bc2 = __shfl(Cv.z, dnL);
                    float ba3 = __shfl(A.w, upL), bc3 = __shfl(Cv.w, dnL);
                    float b0 = v1 ? (hi ? bc0 : ba0) : 0.f;  // cndmask: garbage-safe
                    float b1 = v1 ? (hi ? bc1 : ba1) : 0.f;
                    float b2 = v1 ? (hi ? bc2 : ba2) : 0.f;
                    float b3 = v1 ? (hi ? bc3 : ba3) : 0.f;
                    float pv[12] = {A.x * m0, A.y * m0, A.z * m0, A.w * m0,
                                    b0, b1, b2, b3,
                                    Cv.x * m2, Cv.y * m2, Cv.z * m2, Cv.w * m2};
                    #pragma unroll
                    for (int o = 0; o < 4; ++o)
                        t[rr][o] = W[0] * pv[Mv + o]     + W[1] * pv[Mv + o + 1]
                                 + W[2] * pv[Mv + o + 2] + W[3] * pv[Mv + o + 3];
                }
            };
            switch (M) {
                case 0: rows(std::integral_constant<int, 0>{}); break;
                case 1: rows(std::integral_constant<int, 1>{}); break;
                case 2: rows(std::integral_constant<int, 2>{}); break;
                default: rows(std::integral_constant<int, 3>{}); break;
            }

            if (g.x > 255.0f) {
                float cx31 = g.x + 15.5f;
                float dc   = 272.f - cx31;
                float c272 = __expf(-NS * dc * dc);
                float dD   = 1.f / (Sx - c272 + EPSN) - Dxc;
                float e31[4];
                #pragma unroll
                for (int o = 0; o < 4; ++o) {
                    float d = zx0 + (float)o - 31.f;
                    e31[o] = __expf(-NS * d * d) * dD;
                }
                #pragma unroll
                for (int rr = 0; rr < 5; ++rr) {
                    int src = min(max(pbase + 2 * ysub + rr, 0), 31);
                    float p31 = Pc[(src << 5) + 31];
                    #pragma unroll
                    for (int o = 0; o < 4; ++o) t[rr][o] += e31[o] * p31;
                }
            }

            const float psy = zy0 - floorf(zy0);
            float Ey[4];
            #pragma unroll
            for (int k = 0; k < 4; ++k) {
                float d = psy + (float)(1 - k);
                Ey[k] = __expf(-NS * d * d);
            }
            float Sy   = ((Ey[0] + Ey[1]) + (Ey[2] + Ey[3]));
            float DyC  = (1.f / (Sy + EPSN)) * (1.0f / (float)NN);
            float Dy31 = DyC;
            if (g.y > 254.9f) {
                float cy31 = g.y + 15.6f;
                float dc   = 272.f - cy31;
                float c272 = __expf(-NS * dc * dc);
                Dy31 = (1.f / (Sy - c272 + EPSN)) * (1.0f / (float)NN);
            }
            float wyA[4], wyB[4];
            #pragma unroll
            for (int k = 0; k < 4; ++k) {
                int rA = pbase + 2 * ysub + k;
                int rB = rA + 1;
                wyA[k] = ((unsigned)rA < 32u) ? Ey[k] * ((rA == 31) ? Dy31 : DyC) : 0.f;
                wyB[k] = ((unsigned)rB < 32u) ? Ey[k] * ((rB == 31) ? Dy31 : DyC) : 0.f;
            }
            #pragma unroll
            for (int o = 0; o < 4; ++o) {
                acc[0][o] += wyA[0] * t[0][o] + wyA[1] * t[1][o]
                           + wyA[2] * t[2][o] + wyA[3] * t[3][o];
                acc[1][o] += wyB[0] * t[1][o] + wyB[1] * t[2][o]
                           + wyB[2] * t[3][o] + wyB[3] * t[4][o];
            }
        }
    }

    #pragma unroll
    for (int j = 0; j < 2; ++j) {
        float* o = out + (((size_t)b * NC + cc) * IMG_H + ay0 + j) * IMG_W + ax0;
        *(float4*)o = make_float4(acc[j][0], acc[j][1], acc[j][2], acc[j][3]);
    }
}

extern "C" void kernel_launch(void* const* d_in, const int* in_sizes, int n_in,
                              void* d_out, int out_size, void* d_ws, size_t ws_size,
                              hipStream_t stream) {
    const float* brushes = (const float*)d_in[0];   // (16, 64, 2) f32
    const float* patches = (const float*)d_in[1];   // (16, 64, 3, 32, 32) f32
    float* out = (float*)d_out;                     // (16, 3, 256, 256) f32

    // Diagnostic A/B/C: all three compute the full (identical) output;
    // the last launch (A = verified R9 base) is authoritative for validation.
    fusedB_t32x16<<<NWG, 192, 0, stream>>>(brushes, patches, out);
    fusedC_shfl  <<<NWG, 192, 0, stream>>>(brushes, patches, out);
    fusedA_base  <<<NWG, 192, 0, stream>>>(brushes, patches, out);
}

// Round 13
// 25.405 us; speedup vs baseline: 2.9054x; 2.9054x over previous
//
#include <hip/hip_runtime.h>
#include <type_traits>

#define IMG_W 256
#define IMG_H 256
#define EPSN 1e-7f
#define NS 50.0f            // 1/(2*0.1^2)
#define NB 16
#define NN 64
#define NC 3
#define PH 32
#define PW 32
#define WIN 36
#define NWG 2048            // 128 tiles/image * 16 images

// One block per 32x16 tile, 192 threads (3c x 8ysub x 8xgrp), thread owns
// 4x x 2y. Stroke loop barrier-free / LDS-free; inner math identical to the
// verified R9 kernel. Geometry: 8 x-tiles x 16 y-tiles per image.
__global__ __launch_bounds__(192)
void fused_kernel(const float* __restrict__ brushes,
                  const float* __restrict__ patches,
                  float* __restrict__ out) {
    __shared__ float2 sG[NN];
    __shared__ int    sN[NN];
    __shared__ int    sCnt;

    // XCD-contiguous swizzle: each XCD owns 256 consecutive tiles = 2 images
    int blk = blockIdx.x;
    blk = (blk & 7) * (NWG >> 3) + (blk >> 3);

    const int b    = blk >> 7;
    const int t7   = blk & 127;
    const int ty0  = (t7 >> 3) * 16;            // 16 y-tiles
    const int tx0  = (t7 & 7) * 32;             // 8 x-tiles
    const int tid  = threadIdx.x;
    const int cc   = tid >> 6;
    const int lane = tid & 63;
    const int ysub = lane >> 3;                 // 0..7 -> y rows 2*ysub, 2*ysub+1
    const int xgrp = lane & 7;                  // 0..7 -> x group of 4
    const int ax0  = tx0 + xgrp * 4;
    const int ay0  = ty0 + ysub * 2;

    // --- wave 0: fused per-image min/max norm + ballot overlap list ---
    if (tid < 64) {
        float2 v = ((const float2*)brushes)[b * NN + tid];
        float mnx = v.x, mxx = v.x, mny = v.y, mxy = v.y;
        #pragma unroll
        for (int off = 32; off > 0; off >>= 1) {
            mnx = fminf(mnx, __shfl_xor(mnx, off));
            mxx = fmaxf(mxx, __shfl_xor(mxx, off));
            mny = fminf(mny, __shfl_xor(mny, off));
            mxy = fmaxf(mxy, __shfl_xor(mxy, off));
        }
        float gx = (v.x - mnx) / (mxx - mnx + EPSN) * (float)IMG_W;
        float gy = (v.y - mny) / (mxy - mny + EPSN) * (float)IMG_H;
        int ix0 = (int)floorf(gx) - 17;
        int iy0 = (int)floorf(gy) - 17;
        bool ov = (ix0 <= tx0 + 31) && (ix0 + 35 >= tx0) &&
                  (iy0 <= ty0 + 15) && (iy0 + 35 >= ty0);
        unsigned long long mask = __ballot(ov);
        if (ov) {
            int pos = __popcll(mask & ((1ull << tid) - 1));
            sN[pos] = tid;
            sG[pos] = make_float2(gx, gy);
        }
        if (tid == 0) sCnt = (int)__popcll(mask);
    }
    __syncthreads();                            // only barrier in the kernel
    const int cnt = sCnt;

    float acc[2][4];
    #pragma unroll
    for (int j = 0; j < 2; ++j)
        #pragma unroll
        for (int o = 0; o < 4; ++o) acc[j][o] = 0.f;

    const float* Pcb = patches + (size_t)b * NN * (NC * PH * PW) + cc * (PH * PW);

    for (int i = 0; i < cnt; ++i) {
        const float2 g = sG[i];
        const int    n = sN[i];
        const float* Pc = Pcb + (size_t)n * (NC * PH * PW);

        const float zy0 = (float)ty0 - g.y + 15.4f;
        const int pbase = (int)floorf(zy0) - 1; // p0(yi) = pbase + yi exactly
        const float zx0 = (float)ax0 - g.x + 15.5f;
        const int   q00 = (int)floorf(zx0) - 1;

        if (q00 >= -6 && q00 <= 31) {           // proven active window
            // --- 4 x-Gaussians; their lattice sum IS the (interior) denom ---
            const float phx = zx0 - floorf(zx0);
            float Ex[4], W[4];
            #pragma unroll
            for (int k = 0; k < 4; ++k) {
                float d = phx + (float)(1 - k);
                Ex[k] = __expf(-NS * d * d);
            }
            float Sx  = ((Ex[0] + Ex[1]) + (Ex[2] + Ex[3]));
            float Dxc = 1.f / (Sx + EPSN);
            #pragma unroll
            for (int k = 0; k < 4; ++k) W[k] = Ex[k] * Dxc;

            const int qg = ((q00 + 8) & ~3) - 8;    // [-8,28], multiple of 4
            const int M  = (q00 + 8) & 3;           // wave-uniform per stroke
            const int s1 = qg + 4, s2 = qg + 8;
            const float m0 = (qg >= 0 && qg <= 28) ? 1.f : 0.f;
            const float m1 = (s1 >= 0 && s1 <= 28) ? 1.f : 0.f;
            const float m2 = (s2 >= 0 && s2 <= 28) ? 1.f : 0.f;
            const int c0 = min(max(qg, 0), 28);
            const int c1 = min(max(s1, 0), 28);
            const int c2 = min(max(s2, 0), 28);

            float t[5][4];
            auto rows = [&](auto Mc) {
                constexpr int Mv = Mc.value;
                #pragma unroll
                for (int rr = 0; rr < 5; ++rr) {
                    int src = min(max(pbase + 2 * ysub + rr, 0), 31);
                    const float* rp = Pc + (src << 5);
                    float4 A  = *(const float4*)(rp + c0);
                    float4 Bv = *(const float4*)(rp + c1);
                    float4 Cv = *(const float4*)(rp + c2);
                    float pv[12] = {A.x * m0, A.y * m0, A.z * m0, A.w * m0,
                                    Bv.x * m1, Bv.y * m1, Bv.z * m1, Bv.w * m1,
                                    Cv.x * m2, Cv.y * m2, Cv.z * m2, Cv.w * m2};
                    #pragma unroll
                    for (int o = 0; o < 4; ++o)
                        t[rr][o] = W[0] * pv[Mv + o]     + W[1] * pv[Mv + o + 1]
                                 + W[2] * pv[Mv + o + 2] + W[3] * pv[Mv + o + 3];
                }
            };
            switch (M) {
                case 0: rows(std::integral_constant<int, 0>{}); break;
                case 1: rows(std::integral_constant<int, 1>{}); break;
                case 2: rows(std::integral_constant<int, 2>{}); break;
                default: rows(std::integral_constant<int, 3>{}); break;
            }

            // --- x boundary-denominator correction (a=272 clipped, tap 31) ---
            if (g.x > 255.0f) {
                float cx31 = g.x + 15.5f;
                float dc   = 272.f - cx31;
                float c272 = __expf(-NS * dc * dc);
                float dD   = 1.f / (Sx - c272 + EPSN) - Dxc;
                float e31[4];
                #pragma unroll
                for (int o = 0; o < 4; ++o) {
                    float d = zx0 + (float)o - 31.f;
                    e31[o] = __expf(-NS * d * d) * dD;  // self-gating (0 if far)
                }
                #pragma unroll
                for (int rr = 0; rr < 5; ++rr) {
                    int src = min(max(pbase + 2 * ysub + rr, 0), 31);
                    float p31 = Pc[(src << 5) + 31];
                    #pragma unroll
                    for (int o = 0; o < 4; ++o) t[rr][o] += e31[o] * p31;
                }
            }

            // --- y weights: validity + boundary correction folded in ---
            const float psy = zy0 - floorf(zy0);
            float Ey[4];
            #pragma unroll
            for (int k = 0; k < 4; ++k) {
                float d = psy + (float)(1 - k);
                Ey[k] = __expf(-NS * d * d);
            }
            float Sy   = ((Ey[0] + Ey[1]) + (Ey[2] + Ey[3]));
            float DyC  = (1.f / (Sy + EPSN)) * (1.0f / (float)NN);
            float Dy31 = DyC;
            if (g.y > 254.9f) {
                float cy31 = g.y + 15.6f;
                float dc   = 272.f - cy31;
                float c272 = __expf(-NS * dc * dc);
                Dy31 = (1.f / (Sy - c272 + EPSN)) * (1.0f / (float)NN);
            }
            float wyA[4], wyB[4];
            #pragma unroll
            for (int k = 0; k < 4; ++k) {
                int rA = pbase + 2 * ysub + k;
                int rB = rA + 1;
                wyA[k] = ((unsigned)rA < 32u) ? Ey[k] * ((rA == 31) ? Dy31 : DyC) : 0.f;
                wyB[k] = ((unsigned)rB < 32u) ? Ey[k] * ((rB == 31) ? Dy31 : DyC) : 0.f;
            }

            // --- y-combine (all indices static) ---
            #pragma unroll
            for (int o = 0; o < 4; ++o) {
                acc[0][o] += wyA[0] * t[0][o] + wyA[1] * t[1][o]
                           + wyA[2] * t[2][o] + wyA[3] * t[3][o];
                acc[1][o] += wyB[0] * t[1][o] + wyB[1] * t[2][o]
                           + wyB[2] * t[3][o] + wyB[3] * t[4][o];
            }
        }
    }

    // coalesced float4 stores; tiles partition the image
    #pragma unroll
    for (int j = 0; j < 2; ++j) {
        float* o = out + (((size_t)b * NC + cc) * IMG_H + ay0 + j) * IMG_W + ax0;
        *(float4*)o = make_float4(acc[j][0], acc[j][1], acc[j][2], acc[j][3]);
    }
}

extern "C" void kernel_launch(void* const* d_in, const int* in_sizes, int n_in,
                              void* d_out, int out_size, void* d_ws, size_t ws_size,
                              hipStream_t stream) {
    const float* brushes = (const float*)d_in[0];   // (16, 64, 2) f32
    const float* patches = (const float*)d_in[1];   // (16, 64, 3, 32, 32) f32
    float* out = (float*)d_out;                     // (16, 3, 256, 256) f32

    fused_kernel<<<NWG, 192, 0, stream>>>(brushes, patches, out);
}

// Round 14
// 23.824 us; speedup vs baseline: 3.0983x; 1.0664x over previous
//
#include <hip/hip_runtime.h>
#include <type_traits>

#define IMG_W 256
#define IMG_H 256
#define EPSN 1e-7f
#define NS 50.0f            // 1/(2*0.1^2)
#define NB 16
#define NN 64
#define NC 3
#define PH 32
#define PW 32
#define NWG 2048            // 128 tiles/image * 16 images

// One block per 32x16 tile, 192 threads (3c x 8ysub x 8xgrp), thread owns
// 4x x 2y. Stroke loop barrier-free / LDS-free. Stroke-uniform weights
// (Ex/W/Ey/DyC/Dy31/pbase) hoisted into the wave-0 ballot phase: phx=frac(zx0)
// is a pure stroke property (ax0 % 4 == 0), zy0 is block-uniform.
__global__ __launch_bounds__(192)
void fused_kernel(const float* __restrict__ brushes,
                  const float* __restrict__ patches,
                  float* __restrict__ out) {
    __shared__ float2 sG[NN];       // gx, gy
    __shared__ int    sN[NN];       // stroke index
    __shared__ int    sPb[NN];      // pbase (block-uniform per stroke)
    __shared__ float  sSx[NN];      // x lattice sum (for rare edge fix)
    __shared__ float4 sWx[NN];      // normalized x weights
    __shared__ float4 sEyC[NN];     // Ey * DyC  (incl. 1/N)
    __shared__ float4 sEy31[NN];    // Ey * Dy31 (incl. 1/N)
    __shared__ int    sCnt;

    // XCD-contiguous swizzle: each XCD owns 256 consecutive tiles = 2 images
    int blk = blockIdx.x;
    blk = (blk & 7) * (NWG >> 3) + (blk >> 3);

    const int b    = blk >> 7;
    const int t7   = blk & 127;
    const int ty0  = (t7 >> 3) * 16;            // 16 y-tiles
    const int tx0  = (t7 & 7) * 32;             // 8 x-tiles
    const int tid  = threadIdx.x;
    const int cc   = tid >> 6;
    const int lane = tid & 63;
    const int ysub = lane >> 3;                 // 0..7 -> y rows 2*ysub, 2*ysub+1
    const int xgrp = lane & 7;                  // 0..7 -> x group of 4
    const int ax0  = tx0 + xgrp * 4;
    const int ay0  = ty0 + ysub * 2;

    // --- wave 0: norm + ballot overlap list + per-stroke weight precompute ---
    if (tid < 64) {
        float2 v = ((const float2*)brushes)[b * NN + tid];
        float mnx = v.x, mxx = v.x, mny = v.y, mxy = v.y;
        #pragma unroll
        for (int off = 32; off > 0; off >>= 1) {
            mnx = fminf(mnx, __shfl_xor(mnx, off));
            mxx = fmaxf(mxx, __shfl_xor(mxx, off));
            mny = fminf(mny, __shfl_xor(mny, off));
            mxy = fmaxf(mxy, __shfl_xor(mxy, off));
        }
        float gx = (v.x - mnx) / (mxx - mnx + EPSN) * (float)IMG_W;
        float gy = (v.y - mny) / (mxy - mny + EPSN) * (float)IMG_H;
        int ix0 = (int)floorf(gx) - 17;
        int iy0 = (int)floorf(gy) - 17;
        bool ov = (ix0 <= tx0 + 31) && (ix0 + 35 >= tx0) &&
                  (iy0 <= ty0 + 15) && (iy0 + 35 >= ty0);
        unsigned long long mask = __ballot(ov);
        if (ov) {
            int pos = __popcll(mask & ((1ull << tid) - 1));
            sN[pos] = tid;
            sG[pos] = make_float2(gx, gy);

            // ---- x weights: phx = frac(zx0) is stroke-pure (ax0 % 4 == 0) ----
            float px  = 15.5f - gx;
            float phx = px - floorf(px);
            float Ex[4];
            #pragma unroll
            for (int k = 0; k < 4; ++k) {
                float d = phx + (float)(1 - k);
                Ex[k] = __expf(-NS * d * d);
            }
            float Sx  = ((Ex[0] + Ex[1]) + (Ex[2] + Ex[3]));
            float Dxc = 1.f / (Sx + EPSN);
            sSx[pos] = Sx;
            sWx[pos] = make_float4(Ex[0] * Dxc, Ex[1] * Dxc,
                                   Ex[2] * Dxc, Ex[3] * Dxc);

            // ---- y weights: zy0 block-uniform ----
            float zy0 = (float)ty0 - gy + 15.4f;
            float fz  = floorf(zy0);
            sPb[pos]  = (int)fz - 1;
            float psy = zy0 - fz;
            float Ey[4];
            #pragma unroll
            for (int k = 0; k < 4; ++k) {
                float d = psy + (float)(1 - k);
                Ey[k] = __expf(-NS * d * d);
            }
            float Sy  = ((Ey[0] + Ey[1]) + (Ey[2] + Ey[3]));
            float DyC = (1.f / (Sy + EPSN)) * (1.0f / (float)NN);
            float Dy31 = DyC;
            if (gy > 254.9f) {                  // b=272 clipped for tap row 31
                float cy31 = gy + 15.6f;
                float dc   = 272.f - cy31;
                float c272 = __expf(-NS * dc * dc);
                Dy31 = (1.f / (Sy - c272 + EPSN)) * (1.0f / (float)NN);
            }
            sEyC[pos]  = make_float4(Ey[0] * DyC,  Ey[1] * DyC,
                                     Ey[2] * DyC,  Ey[3] * DyC);
            sEy31[pos] = make_float4(Ey[0] * Dy31, Ey[1] * Dy31,
                                     Ey[2] * Dy31, Ey[3] * Dy31);
        }
        if (tid == 0) sCnt = (int)__popcll(mask);
    }
    __syncthreads();                            // only barrier in the kernel
    const int cnt = sCnt;

    float acc[2][4];
    #pragma unroll
    for (int j = 0; j < 2; ++j)
        #pragma unroll
        for (int o = 0; o < 4; ++o) acc[j][o] = 0.f;

    const float* Pcb = patches + (size_t)b * NN * (NC * PH * PW) + cc * (PH * PW);

    for (int i = 0; i < cnt; ++i) {
        const float2 g = sG[i];                 // LDS broadcast
        const int    n = sN[i];
        const float* Pc = Pcb + (size_t)n * (NC * PH * PW);

        const float zx0 = (float)ax0 - g.x + 15.5f;
        const int   q00 = (int)floorf(zx0) - 1;

        if (q00 >= -6 && q00 <= 31) {           // proven active window
            const float4 W4 = sWx[i];           // broadcast
            const float  W[4] = {W4.x, W4.y, W4.z, W4.w};
            const int    pb = sPb[i];

            const int qg = ((q00 + 8) & ~3) - 8;    // [-8,28], multiple of 4
            const int M  = (q00 + 8) & 3;           // wave-uniform per stroke
            const int s1 = qg + 4, s2 = qg + 8;
            const float m0 = (qg >= 0 && qg <= 28) ? 1.f : 0.f;
            const float m1 = (s1 >= 0 && s1 <= 28) ? 1.f : 0.f;
            const float m2 = (s2 >= 0 && s2 <= 28) ? 1.f : 0.f;
            const int c0 = min(max(qg, 0), 28);
            const int c1 = min(max(s1, 0), 28);
            const int c2 = min(max(s2, 0), 28);

            float t[5][4];
            auto rows = [&](auto Mc) {
                constexpr int Mv = Mc.value;
                #pragma unroll
                for (int rr = 0; rr < 5; ++rr) {
                    int src = min(max(pb + 2 * ysub + rr, 0), 31);
                    const float* rp = Pc + (src << 5);
                    float4 A  = *(const float4*)(rp + c0);
                    float4 Bv = *(const float4*)(rp + c1);
                    float cx0 = 0.f, cx1 = 0.f, cx2 = 0.f, cx3 = 0.f;
                    if constexpr (Mv >= 2) {    // chunk C statically dead for M<2
                        float4 Cv = *(const float4*)(rp + c2);
                        cx0 = Cv.x * m2; cx1 = Cv.y * m2;
                        cx2 = Cv.z * m2; cx3 = Cv.w * m2;
                    }
                    float pv[12] = {A.x * m0, A.y * m0, A.z * m0, A.w * m0,
                                    Bv.x * m1, Bv.y * m1, Bv.z * m1, Bv.w * m1,
                                    cx0, cx1, cx2, cx3};
                    #pragma unroll
                    for (int o = 0; o < 4; ++o)
                        t[rr][o] = W[0] * pv[Mv + o]     + W[1] * pv[Mv + o + 1]
                                 + W[2] * pv[Mv + o + 2] + W[3] * pv[Mv + o + 3];
                }
            };
            switch (M) {
                case 0: rows(std::integral_constant<int, 0>{}); break;
                case 1: rows(std::integral_constant<int, 1>{}); break;
                case 2: rows(std::integral_constant<int, 2>{}); break;
                default: rows(std::integral_constant<int, 3>{}); break;
            }

            // --- x boundary-denominator correction (a=272 clipped, tap 31) ---
            if (g.x > 255.0f) {
                float Sx_  = sSx[i];
                float Dxc_ = 1.f / (Sx_ + EPSN);
                float cx31 = g.x + 15.5f;
                float dc   = 272.f - cx31;
                float c272 = __expf(-NS * dc * dc);
                float dD   = 1.f / (Sx_ - c272 + EPSN) - Dxc_;
                float e31[4];
                #pragma unroll
                for (int o = 0; o < 4; ++o) {
                    float d = zx0 + (float)o - 31.f;
                    e31[o] = __expf(-NS * d * d) * dD;  // self-gating (0 if far)
                }
                #pragma unroll
                for (int rr = 0; rr < 5; ++rr) {
                    int src = min(max(pb + 2 * ysub + rr, 0), 31);
                    float p31 = Pc[(src << 5) + 31];
                    #pragma unroll
                    for (int o = 0; o < 4; ++o) t[rr][o] += e31[o] * p31;
                }
            }

            // --- y weights from precomputed products; validity by select ---
            const float4 eC = sEyC[i];
            const float4 e3 = sEy31[i];
            const float eyC[4]  = {eC.x, eC.y, eC.z, eC.w};
            const float ey31[4] = {e3.x, e3.y, e3.z, e3.w};
            float wyA[4], wyB[4];
            #pragma unroll
            for (int k = 0; k < 4; ++k) {
                int rA = pb + 2 * ysub + k;
                int rB = rA + 1;
                wyA[k] = ((unsigned)rA < 32u) ? ((rA == 31) ? ey31[k] : eyC[k]) : 0.f;
                wyB[k] = ((unsigned)rB < 32u) ? ((rB == 31) ? ey31[k] : eyC[k]) : 0.f;
            }

            // --- y-combine (all indices static) ---
            #pragma unroll
            for (int o = 0; o < 4; ++o) {
                acc[0][o] += wyA[0] * t[0][o] + wyA[1] * t[1][o]
                           + wyA[2] * t[2][o] + wyA[3] * t[3][o];
                acc[1][o] += wyB[0] * t[1][o] + wyB[1] * t[2][o]
                           + wyB[2] * t[3][o] + wyB[3] * t[4][o];
            }
        }
    }

    // coalesced float4 stores; tiles partition the image
    #pragma unroll
    for (int j = 0; j < 2; ++j) {
        float* o = out + (((size_t)b * NC + cc) * IMG_H + ay0 + j) * IMG_W + ax0;
        *(float4*)o = make_float4(acc[j][0], acc[j][1], acc[j][2], acc[j][3]);
    }
}

extern "C" void kernel_launch(void* const* d_in, const int* in_sizes, int n_in,
                              void* d_out, int out_size, void* d_ws, size_t ws_size,
                              hipStream_t stream) {
    const float* brushes = (const float*)d_in[0];   // (16, 64, 2) f32
    const float* patches = (const float*)d_in[1];   // (16, 64, 3, 32, 32) f32
    float* out = (float*)d_out;                     // (16, 3, 256, 256) f32

    fused_kernel<<<NWG, 192, 0, stream>>>(brushes, patches, out);
}